// Round 2
// 467.709 us; speedup vs baseline: 1.1520x; 1.1520x over previous
//
#include <hip/hip_runtime.h>

// WordAttention: mix = softmax(relu(c@W^T+b) @ relu(q@W^T+b)^T) @ q
// B=32, CL=2048, QL=512, DIM=512, fp32 in/out, fp16 MFMA compute (fp32 accum).
// R4 (resubmit; R1 bench was a broker timeout, no signal): fused kernel =
// proj(c) + scores + softmax + mix in one block (CT=64 rows, 8 waves).
// Batch-affinity XCD swizzle keeps each XCD's qfS/qTS slices (<=2 batches =
// 2.5MB incl. W) resident in its own 4MB L2 -- previously the fragment
// stream (2.1GB/dispatch) thrashed L2 and ran at the L3 ceiling.
// LDS A-tile uses T2-style 16B-unit XOR swizzle (u ^= row&7), no pad.

#define BATCH 32
#define CL    2048
#define QL    512
#define DIM   512
#define CT    64      // c-rows per fused workgroup

typedef _Float16 f16x8 __attribute__((ext_vector_type(8)));
typedef _Float16 f16x4 __attribute__((ext_vector_type(4)));
typedef float    f32x4 __attribute__((ext_vector_type(4)));

#define LDP 72    // proj A-stage row (halfs): bank offset 36 dwords -> 2-way, free

// ---- shuffle row-major fp16 [M][512] into fragment-major [M/16][16][64][8] ----
__global__ void k_shuf_f16(const _Float16* __restrict__ in, _Float16* __restrict__ out) {
    size_t g = (size_t)blockIdx.x * 256 + threadIdx.x;
    int rt = (int)(g >> 10), ks = (int)(g >> 6) & 15, l = (int)g & 63;
    const _Float16* src = in + ((size_t)(rt * 16 + (l & 15))) * 512 + ks * 32 + (l >> 4) * 8;
    *(uint4*)(out + g * 8) = *(const uint4*)src;
}

// ---- same but fp32 source (used for W) ----
__global__ void k_shuf_f32(const float* __restrict__ in, _Float16* __restrict__ out) {
    size_t g = (size_t)blockIdx.x * 256 + threadIdx.x;
    int rt = (int)(g >> 10), ks = (int)(g >> 6) & 15, l = (int)g & 63;
    const float* src = in + ((size_t)(rt * 16 + (l & 15))) * 512 + ks * 32 + (l >> 4) * 8;
    float4 v0 = *(const float4*)src;
    float4 v1 = *(const float4*)(src + 4);
    f16x8 h = {(_Float16)v0.x, (_Float16)v0.y, (_Float16)v0.z, (_Float16)v0.w,
               (_Float16)v1.x, (_Float16)v1.y, (_Float16)v1.z, (_Float16)v1.w};
    *(f16x8*)(out + g * 8) = h;
}

// ---- prep: qT[b][d][j] = fp16(q[b][j][d]) (row-major; shuffled afterwards) ----
__global__ void k_prep_qt(const float* __restrict__ q, _Float16* __restrict__ qT) {
    __shared__ _Float16 t[64][65];
    int b  = blockIdx.x;
    int jt = blockIdx.y;            // QL/64
    int dt = blockIdx.z;            // DIM/64
    const float* src = q + ((size_t)b * QL + jt * 64) * DIM + dt * 64;
    int r0 = threadIdx.x >> 6;
    int cc = threadIdx.x & 63;
#pragma unroll
    for (int p = 0; p < 16; ++p) {
        int r = r0 + p * 4;
        t[r][cc] = (_Float16)src[(size_t)r * DIM + cc];
    }
    __syncthreads();
    _Float16* dst = qT + ((size_t)b * DIM + dt * 64) * QL + jt * 64;
#pragma unroll
    for (int p = 0; p < 16; ++p) {
        int r = r0 + p * 4;
        dst[(size_t)r * QL + cc] = t[cc][r];
    }
}

// ---- Y = relu(X @ W^T + b) fp16, 128x128 tiles, K=512 (q path only now) ----
__global__ __launch_bounds__(256)
__attribute__((amdgpu_waves_per_eu(3)))
void k_proj(const float* __restrict__ X, const _Float16* __restrict__ WhS,
            const float* __restrict__ bias, _Float16* __restrict__ Y) {
    __shared__ __align__(16) _Float16 Ah[128 * LDP];
    int m0 = blockIdx.x * 128;
    int n0 = blockIdx.y * 128;
    int tid = threadIdx.x;
    int w = tid >> 6, lane = tid & 63;
    int col = lane & 15, quad = lane >> 4;
    int wm = (w >> 1) * 64, wn = (w & 1) * 64;
    int et0 = (n0 + wn) >> 4;

    f32x4 acc[4][4];
#pragma unroll
    for (int it = 0; it < 4; ++it)
#pragma unroll
        for (int jt = 0; jt < 4; ++jt) acc[it][jt] = (f32x4){0.f, 0.f, 0.f, 0.f};

    for (int kc = 0; kc < 8; ++kc) {       // BK=64
#pragma unroll
        for (int p = 0; p < 8; ++p) {
            int s = tid + p * 256;
            int r = s >> 4, c4 = (s & 15) * 4;
            float4 v = *(const float4*)(X + (size_t)(m0 + r) * DIM + kc * 64 + c4);
            f16x4 h = {(_Float16)v.x, (_Float16)v.y, (_Float16)v.z, (_Float16)v.w};
            *(f16x4*)&Ah[r * LDP + c4] = h;
        }
        __syncthreads();
#pragma unroll
        for (int kc2 = 0; kc2 < 2; ++kc2) {
            int ks = kc * 2 + kc2;
            f16x8 af[4], bf[4];
#pragma unroll
            for (int it = 0; it < 4; ++it)
                af[it] = *(const f16x8*)&Ah[(wm + it * 16 + col) * LDP + kc2 * 32 + quad * 8];
#pragma unroll
            for (int jt = 0; jt < 4; ++jt)
                bf[jt] = *(const f16x8*)(WhS + (((size_t)(et0 + jt) * 16 + ks) * 64 + lane) * 8);
#pragma unroll
            for (int it = 0; it < 4; ++it)
#pragma unroll
                for (int jt = 0; jt < 4; ++jt)
                    acc[it][jt] = __builtin_amdgcn_mfma_f32_16x16x32_f16(af[it], bf[jt], acc[it][jt], 0, 0, 0);
        }
        __syncthreads();
    }
#pragma unroll
    for (int jt = 0; jt < 4; ++jt) {
        int e = n0 + wn + jt * 16 + col;
        float bv = bias[e];
#pragma unroll
        for (int it = 0; it < 4; ++it)
#pragma unroll
            for (int r = 0; r < 4; ++r) {
                int row = m0 + wm + it * 16 + quad * 4 + r;
                Y[(size_t)row * DIM + e] = (_Float16)fmaxf(acc[it][jt][r] + bv, 0.f);
            }
    }
}

// ---- fused: cf = relu(c@W^T+b) ; S = cf@qf^T ; softmax ; out = P@q ----
// 512 threads (8 waves), CT=64 c-rows per block. Each wave owns a 64-wide
// j/e/d column slice. A-tile At[64][512] fp16 in LDS, XOR-swizzled in 16B
// units: element [row][e] lives at row*512 + (((e>>3) ^ (row&7))<<3) + (e&7).
__global__ __launch_bounds__(512)
__attribute__((amdgpu_waves_per_eu(4)))
void k_fused(const float* __restrict__ C, const _Float16* __restrict__ WhS,
             const float* __restrict__ bias,
             const _Float16* __restrict__ qfS, const _Float16* __restrict__ qTS,
             float* __restrict__ out) {
    __shared__ __align__(16) _Float16 At[CT * DIM];   // 64 KB
    __shared__ float redmax[8][CT];
    __shared__ float redsum[8][CT];

    // batch-affinity XCD swizzle: XCD x (= blockIdx%8 under round-robin
    // dispatch) runs only batches b ≡ x (mod 8); <=2 batches concurrent/XCD.
    int bx   = blockIdx.x;
    int xcd  = bx & 7;
    int slot = bx >> 3;                 // 0..127 per XCD
    int b    = xcd + 8 * (slot >> 5);   // 4 batches per XCD, 2 concurrent
    int c0   = (slot & 31) * CT;

    int tid   = threadIdx.x;
    int w     = tid >> 6, lane = tid & 63;
    int col   = lane & 15, quad = lane >> 4;
    int obase = w * 64;                 // this wave's column slice
    int cs    = col & 7;                // XOR key: A-frag rows are it*16+col

    // ---- stage c tile: 64 rows x 512 fp32 -> fp16, swizzled ----
    const float* cb = C + ((size_t)b * CL + c0) * DIM;
#pragma unroll
    for (int p = 0; p < 8; ++p) {
        int s = tid + p * 512;          // 0..4095
        int r = s >> 6, u = s & 63;     // row, 16B unit
        const float* src = cb + (size_t)r * DIM + u * 8;
        float4 v0 = *(const float4*)src;
        float4 v1 = *(const float4*)(src + 4);
        f16x8 h = {(_Float16)v0.x, (_Float16)v0.y, (_Float16)v0.z, (_Float16)v0.w,
                   (_Float16)v1.x, (_Float16)v1.y, (_Float16)v1.z, (_Float16)v1.w};
        *(f16x8*)&At[r * DIM + ((u ^ (r & 7)) << 3)] = h;
    }
    __syncthreads();

    f32x4 acc[4][4];

    // ---- phase 0: cf = relu(c @ W^T + bias), W stream from L2 ----
#pragma unroll
    for (int it = 0; it < 4; ++it)
#pragma unroll
        for (int jt = 0; jt < 4; ++jt) acc[it][jt] = (f32x4){0.f, 0.f, 0.f, 0.f};
    {
        int et0 = w * 4;
#pragma unroll 2
        for (int kc = 0; kc < 16; ++kc) {
            int ku = kc * 4 + quad;
            f16x8 af[4], bf[4];
#pragma unroll
            for (int it = 0; it < 4; ++it)
                af[it] = *(const f16x8*)&At[(it * 16 + col) * DIM + ((ku ^ cs) << 3)];
#pragma unroll
            for (int jt = 0; jt < 4; ++jt)
                bf[jt] = *(const f16x8*)(WhS + (((size_t)(et0 + jt) * 16 + kc) * 64 + lane) * 8);
#pragma unroll
            for (int it = 0; it < 4; ++it)
#pragma unroll
                for (int jt = 0; jt < 4; ++jt)
                    acc[it][jt] = __builtin_amdgcn_mfma_f32_16x16x32_f16(af[it], bf[jt], acc[it][jt], 0, 0, 0);
        }
    }
    __syncthreads();        // all waves done reading the c tile
    // bias + relu -> cf overwrites At (swizzled)
#pragma unroll
    for (int jt = 0; jt < 4; ++jt) {
        int e = obase + jt * 16 + col;
        float bv = bias[e];
        int ue = e >> 3, we = e & 7;
#pragma unroll
        for (int it = 0; it < 4; ++it)
#pragma unroll
            for (int r = 0; r < 4; ++r) {
                int m = it * 16 + quad * 4 + r;
                At[m * DIM + (((ue ^ (m & 7)) << 3) | we)] =
                    (_Float16)fmaxf(acc[it][jt][r] + bv, 0.f);
            }
    }
    __syncthreads();

    // ---- phase 2: S = cf @ qf^T, qf stream from this XCD's L2 ----
#pragma unroll
    for (int it = 0; it < 4; ++it)
#pragma unroll
        for (int jt = 0; jt < 4; ++jt) acc[it][jt] = (f32x4){0.f, 0.f, 0.f, 0.f};
    int rt0 = b * 32 + w * 4;           // fragment row-tile base (this wave's 64 j/d)
#pragma unroll 2
    for (int kc = 0; kc < 16; ++kc) {
        int ku = kc * 4 + quad;
        f16x8 af[4], bf[4];
#pragma unroll
        for (int it = 0; it < 4; ++it)
            af[it] = *(const f16x8*)&At[(it * 16 + col) * DIM + ((ku ^ cs) << 3)];
#pragma unroll
        for (int jt = 0; jt < 4; ++jt)
            bf[jt] = *(const f16x8*)(qfS + (((size_t)(rt0 + jt) * 16 + kc) * 64 + lane) * 8);
#pragma unroll
        for (int it = 0; it < 4; ++it)
#pragma unroll
            for (int jt = 0; jt < 4; ++jt)
                acc[it][jt] = __builtin_amdgcn_mfma_f32_16x16x32_f16(af[it], bf[jt], acc[it][jt], 0, 0, 0);
    }

    // ---- phase 3: softmax over j (512 across 8 waves) ----
    float sm[4][4];
#pragma unroll
    for (int it = 0; it < 4; ++it)
#pragma unroll
        for (int r = 0; r < 4; ++r) {
            float m = -1e30f;
#pragma unroll
            for (int jt = 0; jt < 4; ++jt) m = fmaxf(m, acc[it][jt][r]);
            m = fmaxf(m, __shfl_xor(m, 1));
            m = fmaxf(m, __shfl_xor(m, 2));
            m = fmaxf(m, __shfl_xor(m, 4));
            m = fmaxf(m, __shfl_xor(m, 8));
            sm[it][r] = m;
        }
    if (col == 0) {
#pragma unroll
        for (int it = 0; it < 4; ++it)
#pragma unroll
            for (int r = 0; r < 4; ++r) redmax[w][it * 16 + quad * 4 + r] = sm[it][r];
    }
    __syncthreads();        // also fences phase-2 At reads before P overwrite
#pragma unroll
    for (int it = 0; it < 4; ++it)
#pragma unroll
        for (int r = 0; r < 4; ++r) {
            int i = it * 16 + quad * 4 + r;
            float gm = redmax[0][i];
#pragma unroll
            for (int v = 1; v < 8; ++v) gm = fmaxf(gm, redmax[v][i]);
            float s = 0.f;
#pragma unroll
            for (int jt = 0; jt < 4; ++jt) {
                float e = __expf(acc[it][jt][r] - gm);
                acc[it][jt][r] = e;
                s += e;
            }
            s += __shfl_xor(s, 1);
            s += __shfl_xor(s, 2);
            s += __shfl_xor(s, 4);
            s += __shfl_xor(s, 8);
            sm[it][r] = s;
        }
    if (col == 0) {
#pragma unroll
        for (int it = 0; it < 4; ++it)
#pragma unroll
            for (int r = 0; r < 4; ++r) redsum[w][it * 16 + quad * 4 + r] = sm[it][r];
    }
    __syncthreads();
#pragma unroll
    for (int it = 0; it < 4; ++it)
#pragma unroll
        for (int r = 0; r < 4; ++r) {
            int i = it * 16 + quad * 4 + r;
            float tot = 0.f;
#pragma unroll
            for (int v = 0; v < 8; ++v) tot += redsum[v][i];
            float inv = 1.f / tot;
#pragma unroll
            for (int jt = 0; jt < 4; ++jt) {
                int j = obase + jt * 16 + col;
                int uj = j >> 3, wj = j & 7;
                At[i * DIM + (((uj ^ (i & 7)) << 3) | wj)] =
                    (_Float16)(acc[it][jt][r] * inv);
            }
        }
    __syncthreads();        // P tile visible to all waves

    // ---- phase 4: out = P @ q, qT stream from this XCD's L2 ----
#pragma unroll
    for (int it = 0; it < 4; ++it)
#pragma unroll
        for (int jt = 0; jt < 4; ++jt) acc[it][jt] = (f32x4){0.f, 0.f, 0.f, 0.f};
#pragma unroll 2
    for (int kc = 0; kc < 16; ++kc) {
        int ku = kc * 4 + quad;
        f16x8 af[4], bf[4];
#pragma unroll
        for (int it = 0; it < 4; ++it)
            af[it] = *(const f16x8*)&At[(it * 16 + col) * DIM + ((ku ^ cs) << 3)];
#pragma unroll
        for (int dt = 0; dt < 4; ++dt)
            bf[dt] = *(const f16x8*)(qTS + (((size_t)(rt0 + dt) * 16 + kc) * 64 + lane) * 8);
#pragma unroll
        for (int it = 0; it < 4; ++it)
#pragma unroll
            for (int dt = 0; dt < 4; ++dt)
                acc[it][dt] = __builtin_amdgcn_mfma_f32_16x16x32_f16(af[it], bf[dt], acc[it][dt], 0, 0, 0);
    }

    // ---- epilogue: fp32 out ----
#pragma unroll
    for (int dt = 0; dt < 4; ++dt) {
        int d = obase + dt * 16 + col;
#pragma unroll
        for (int it = 0; it < 4; ++it)
#pragma unroll
            for (int r = 0; r < 4; ++r) {
                int m = it * 16 + quad * 4 + r;
                out[((size_t)b * CL + c0 + m) * DIM + d] = acc[it][dt][r];
            }
    }
}

extern "C" void kernel_launch(void* const* d_in, const int* in_sizes, int n_in,
                              void* d_out, int out_size, void* d_ws, size_t ws_size,
                              hipStream_t stream) {
    const float* c    = (const float*)d_in[0];
    const float* q    = (const float*)d_in[1];
    const float* W    = (const float*)d_in[2];
    const float* bias = (const float*)d_in[3];
    float* out = (float*)d_out;

    // ws: WhS 512K | qfS 16M | qTS 16M | qf 16M | qT 16M
    char* ws = (char*)d_ws;
    _Float16* WhS = (_Float16*)ws;
    _Float16* qfS = (_Float16*)(ws + (1u << 19));
    _Float16* qTS = (_Float16*)(ws + (1u << 19) + (1u << 24));
    _Float16* qf  = (_Float16*)(ws + (1u << 19) + 2u * (1u << 24));
    _Float16* qT  = (_Float16*)(ws + (1u << 19) + 3u * (1u << 24));

    k_shuf_f32<<<128, 256, 0, stream>>>(W, WhS);                          // W -> WhS
    k_proj<<<dim3(BATCH * QL / 128, 4), 256, 0, stream>>>(q, WhS, bias, qf);
    k_shuf_f16<<<4096, 256, 0, stream>>>(qf, qfS);                        // qf -> qfS
    k_prep_qt<<<dim3(BATCH, QL / 64, DIM / 64), 256, 0, stream>>>(q, qT);
    k_shuf_f16<<<4096, 256, 0, stream>>>(qT, qTS);                        // qT -> qTS
    k_fused<<<BATCH * (CL / CT), 512, 0, stream>>>(c, WhS, bias, qfS, qTS, out);
}